// Round 11
// baseline (381.798 us; speedup 1.0000x reference)
//
#include <hip/hip_runtime.h>
#include <hip/hip_bf16.h>

#define NS 256    // n_state
#define MO 128    // n_obs
#define BB 64     // batch
#define TT 1024   // time steps

typedef short s16x8 __attribute__((ext_vector_type(8)));
typedef float f32x4 __attribute__((ext_vector_type(4)));
typedef unsigned int uint;
typedef unsigned short ushort;

__device__ __forceinline__ ushort f2bf(float x) {
    uint u = __float_as_uint(x);
    uint r = (u + 0x7fffu + ((u >> 16) & 1u)) >> 16;
    return (ushort)r;
}
__device__ __forceinline__ float bf2f(ushort h) { return __uint_as_float(((uint)h) << 16); }

__device__ __forceinline__ uint pkbf2(float a, float b) {
    __hip_bfloat162 h = __float22bfloat162_rn(make_float2(a, b));
    union { __hip_bfloat162 b2; uint u; } cv;
    cv.b2 = h;
    return cv.u;
}

// split 8 fp32 into bf16 hi + lo fragments (element order = k ascending)
__device__ __forceinline__ void conv8(float4 f0, float4 f1, s16x8& vh, s16x8& vl) {
    uint h0 = pkbf2(f0.x, f0.y), h1 = pkbf2(f0.z, f0.w);
    uint h2 = pkbf2(f1.x, f1.y), h3 = pkbf2(f1.z, f1.w);
    float r0 = f0.x - __uint_as_float(h0 << 16);
    float r1 = f0.y - __uint_as_float(h0 & 0xffff0000u);
    float r2 = f0.z - __uint_as_float(h1 << 16);
    float r3 = f0.w - __uint_as_float(h1 & 0xffff0000u);
    float r4 = f1.x - __uint_as_float(h2 << 16);
    float r5 = f1.y - __uint_as_float(h2 & 0xffff0000u);
    float r6 = f1.z - __uint_as_float(h3 << 16);
    float r7 = f1.w - __uint_as_float(h3 & 0xffff0000u);
    uint l0 = pkbf2(r0, r1), l1 = pkbf2(r2, r3);
    uint l2 = pkbf2(r4, r5), l3 = pkbf2(r6, r7);
    union { uint u[4]; s16x8 v; } ch, cl;
    ch.u[0] = h0; ch.u[1] = h1; ch.u[2] = h2; ch.u[3] = h3;
    cl.u[0] = l0; cl.u[1] = l1; cl.u[2] = l2; cl.u[3] = l3;
    vh = ch.v; vl = cl.v;
}

__device__ __forceinline__ f32x4 mfma16(s16x8 a, s16x8 b, f32x4 c) {
    return __builtin_amdgcn_mfma_f32_16x16x32_bf16(a, b, c, 0, 0, 0);
}

// device-scope grid barrier (blocks must be co-resident; grid <= 256)
__device__ __forceinline__ void grid_barrier(int* ctr, int target) {
    __syncthreads();
    if (threadIdx.x == 0) {
        __threadfence();
        atomicAdd(ctr, 1);
        while (atomicAdd(ctr, 0) < target) { }
        __threadfence();
    }
    __syncthreads();
}

// ---------------- fused setup: khaeff + 7 squarings, grid-barriered ----------------
// grid 256 x 256. Phase 0: AE = A - (K@H)@A -> Ta (+ kah, aeh/ael).
// Phases 1..7: squaring chain Ta->Tb->... ; A^16 -> mh/ml (phase 4),
// A^128 -> m2h/m2l (phase 7).
__global__ void setup_kernel(const float* __restrict__ K, const float* __restrict__ H,
                             const float* __restrict__ A,
                             float* __restrict__ Ta, float* __restrict__ Tb,
                             ushort* __restrict__ kah,
                             ushort* __restrict__ aeh, ushort* __restrict__ ael,
                             ushort* __restrict__ mh, ushort* __restrict__ ml,
                             ushort* __restrict__ m2h, ushort* __restrict__ m2l,
                             int* bars) {
    const int i = blockIdx.x, j = threadIdx.x;
    __shared__ float kl[MO];
    __shared__ float rowb[NS];

    // phase 0: khaeff
    if (j < MO) {
        float v = K[i * MO + j];
        kl[j] = v;
        kah[i * MO + j] = f2bf(v);
    }
    __syncthreads();
    float acc = 0.f;
#pragma unroll 8
    for (int k = 0; k < MO; ++k) acc += kl[k] * H[k * NS + j];
    rowb[j] = acc;  // KH row i
    __syncthreads();
    float ae = A[i * NS + j];
#pragma unroll 8
    for (int k = 0; k < NS; ++k) ae -= rowb[k] * A[k * NS + j];
    Ta[i * NS + j] = ae;
    ushort hi = f2bf(ae);
    aeh[i * NS + j] = hi;
    ael[i * NS + j] = f2bf(ae - bf2f(hi));
    grid_barrier(&bars[0], 256);

    // phases 1..7: squarings
    const float* src = Ta;
    float* dst = Tb;
#pragma unroll 1
    for (int p = 1; p <= 7; ++p) {
        rowb[j] = src[i * NS + j];
        __syncthreads();
        float a2 = 0.f;
#pragma unroll 8
        for (int k = 0; k < NS; ++k) a2 += rowb[k] * src[k * NS + j];
        dst[i * NS + j] = a2;
        if (p == 4) {
            ushort h2 = f2bf(a2);
            mh[i * NS + j] = h2;
            ml[i * NS + j] = f2bf(a2 - bf2f(h2));
        } else if (p == 7) {
            ushort h2 = f2bf(a2);
            m2h[i * NS + j] = h2;
            m2l[i * NS + j] = f2bf(a2 - bf2f(h2));
        }
        grid_barrier(&bars[p], 256);
        float* t = (float*)src; src = dst; dst = t;
    }
}

// ---------------- scan core (carry modes 1/2/3), identical math to r10 ----------------
template <int MODE>
__device__ __forceinline__ void scan_core(const ushort* __restrict__ mh,
                                          const ushort* __restrict__ ml,
                                          const ushort* __restrict__ ub,
                                          const ushort* __restrict__ cin,
                                          ushort* __restrict__ wbf,
                                          ushort* __restrict__ ebf,
                                          ushort xh_s[2][16 * NS],
                                          ushort xl_s[2][16 * NS]) {
    constexpr int S = (MODE == 1) ? 8 : 7;
    const int tid = threadIdx.x, blk = blockIdx.x;
    const int w = tid >> 6, l = tid & 63, lr = l & 15, lg = l >> 4;

    s16x8 Bh[2][8], Bl[2][8];
#pragma unroll
    for (int t2 = 0; t2 < 2; ++t2) {
        int row = 16 * (2 * w + t2) + lr;
#pragma unroll
        for (int q = 0; q < 8; ++q) {
            int off = row * NS + 32 * q + 8 * lg;
            Bh[t2][q] = *(const s16x8*)(mh + off);
            Bl[t2][q] = *(const s16x8*)(ml + off);
        }
    }

#pragma unroll
    for (int jj = 0; jj < 8; ++jj) {
        int idx = jj * 512 + tid;
        int m = idx >> 8, col = idx & 255;
        ushort hu = 0;
        if constexpr (MODE == 3) {
            int rid = blk * 16 + m;
            int b = rid >> 3, g = rid & 7;
            hu = cin[((long)b * 8 + g) * NS + col];
            wbf[((long)b * 64 + 8 * g) * NS + col] = hu;  // cbuf[b][8g] = carry
        } else if constexpr (MODE == 2) {
            wbf[(long)(blk * 16 + m) * 8 * NS + col] = 0;  // c2[b][0] = 0
        }
        int si = (m * NS + col) ^ ((m & 7) << 3);
        xh_s[0][si] = hu;
        xl_s[0][si] = 0;
    }

    const int st0 = 32 * w + 4 * lg;
    const int st1 = st0 + 16;

    long ubase;
    if constexpr (MODE == 1 || MODE == 3) {
        int rid = blk * 16 + lr;
        ubase = ((long)(rid >> 3) * 64 + 8 * (rid & 7)) * NS;
    } else {
        ubase = (long)(blk * 16 + lr) * 8 * NS;
    }

    auto ldu = [&](long off) -> f32x4 {
        uint2 v = *(const uint2*)(ub + off);
        return f32x4{__uint_as_float(v.x << 16), __uint_as_float(v.x & 0xffff0000u),
                     __uint_as_float(v.y << 16), __uint_as_float(v.y & 0xffff0000u)};
    };

    f32x4 up0 = ldu(ubase + st0);
    f32x4 up1 = ldu(ubase + st1);
    __syncthreads();

    for (int s = 0; s < S; ++s) {
        const int cur = s & 1, nxt = cur ^ 1;

        f32x4 a0a = up0, a0b = {0.f, 0.f, 0.f, 0.f}, a0c = {0.f, 0.f, 0.f, 0.f};
        f32x4 a1a = up1, a1b = {0.f, 0.f, 0.f, 0.f}, a1c = {0.f, 0.f, 0.f, 0.f};
#pragma unroll
        for (int q = 0; q < 8; ++q) {
            int ridx = (lr * NS + 32 * q + 8 * lg) ^ ((lr & 7) << 3);
            s16x8 xh = *(const s16x8*)&xh_s[cur][ridx];
            s16x8 xl = *(const s16x8*)&xl_s[cur][ridx];
            a0a = mfma16(Bh[0][q], xh, a0a);
            a0b = mfma16(Bh[0][q], xl, a0b);
            a0c = mfma16(Bl[0][q], xh, a0c);
            a1a = mfma16(Bh[1][q], xh, a1a);
            a1b = mfma16(Bh[1][q], xl, a1b);
            a1c = mfma16(Bl[1][q], xh, a1c);
        }
        f32x4 acc0 = (a0a + a0b) + a0c;
        f32x4 acc1 = (a1a + a1b) + a1c;

        if (s + 1 < S) {
            up0 = ldu(ubase + (long)(s + 1) * NS + st0);
            up1 = ldu(ubase + (long)(s + 1) * NS + st1);
        }

        uint h01a = pkbf2(acc0[0], acc0[1]), h23a = pkbf2(acc0[2], acc0[3]);
        uint h01b = pkbf2(acc1[0], acc1[1]), h23b = pkbf2(acc1[2], acc1[3]);

        if constexpr (MODE == 2) {
            long wb = ((long)(blk * 16 + lr) * 8 + s + 1) * NS;
            *(uint2*)(wbf + wb + st0) = make_uint2(h01a, h23a);
            *(uint2*)(wbf + wb + st1) = make_uint2(h01b, h23b);
        } else if constexpr (MODE == 3) {
            int rid = blk * 16 + lr;
            long wb = ((long)(rid >> 3) * 64 + 8 * (rid & 7) + s + 1) * NS;
            *(uint2*)(wbf + wb + st0) = make_uint2(h01a, h23a);
            *(uint2*)(wbf + wb + st1) = make_uint2(h01b, h23b);
        } else if constexpr (MODE == 1) {
            if (s == S - 1) {
                int rid = blk * 16 + lr;
                long eb = ((long)(rid >> 3) * 8 + (rid & 7)) * NS;
                *(uint2*)(ebf + eb + st0) = make_uint2(h01a, h23a);
                *(uint2*)(ebf + eb + st1) = make_uint2(h01b, h23b);
            }
        }

        if (s + 1 < S) {
            float la0 = acc0[0] - __uint_as_float(h01a << 16);
            float la1 = acc0[1] - __uint_as_float(h01a & 0xffff0000u);
            float la2 = acc0[2] - __uint_as_float(h23a << 16);
            float la3 = acc0[3] - __uint_as_float(h23a & 0xffff0000u);
            float lb0 = acc1[0] - __uint_as_float(h01b << 16);
            float lb1 = acc1[1] - __uint_as_float(h01b & 0xffff0000u);
            float lb2 = acc1[2] - __uint_as_float(h23b << 16);
            float lb3 = acc1[3] - __uint_as_float(h23b & 0xffff0000u);
            int wi0 = lr * NS + (st0 ^ ((lr & 7) << 3));
            int wi1 = lr * NS + (st1 ^ ((lr & 7) << 3));
            *(uint2*)&xh_s[nxt][wi0] = make_uint2(h01a, h23a);
            *(uint2*)&xh_s[nxt][wi1] = make_uint2(h01b, h23b);
            *(uint2*)&xl_s[nxt][wi0] = make_uint2(pkbf2(la0, la1), pkbf2(la2, la3));
            *(uint2*)&xl_s[nxt][wi1] = make_uint2(pkbf2(lb0, lb1), pkbf2(lb2, lb3));
        }
        __syncthreads();
    }
}

// ---------------- mid kernel: modes 1 -> 2 -> 3 with grid barriers ----------------
__launch_bounds__(512, 1)
__global__ void mid_kernel(const ushort* __restrict__ mh, const ushort* __restrict__ ml,
                           const ushort* __restrict__ m2h, const ushort* __restrict__ m2l,
                           const ushort* __restrict__ e_buf, ushort* __restrict__ e2,
                           ushort* __restrict__ c2, ushort* __restrict__ cbuf,
                           int* bars) {
    __shared__ ushort xh_s[2][16 * NS];
    __shared__ ushort xl_s[2][16 * NS];

    scan_core<1>(mh, ml, e_buf, nullptr, nullptr, e2, xh_s, xl_s);
    grid_barrier(&bars[8], 32);
    if (blockIdx.x < 4) {
        scan_core<2>(m2h, m2l, e2, nullptr, c2, nullptr, xh_s, xl_s);
    }
    grid_barrier(&bars[9], 32);
    scan_core<3>(mh, ml, e_buf, c2, cbuf, nullptr, xh_s, xl_s);
}

// ---------------- fused big scans (modes 0/4), byte-identical math to r10 ----------------
template <int MODE>
__launch_bounds__(512, 1)
__global__ void scan16_kernel(const ushort* __restrict__ mh, const ushort* __restrict__ ml,
                              const ushort* __restrict__ kah,
                              const float* __restrict__ y_g,
                              const ushort* __restrict__ cin, float* outf,
                              ushort* __restrict__ ebf) {
    constexpr int S = 16;
    const int tid = threadIdx.x, blk = blockIdx.x;
    const int w = tid >> 6, l = tid & 63, lr = l & 15, lg = l >> 4;

    __shared__ ushort xh_s[2][16 * NS];
    __shared__ ushort xl_s[2][16 * NS];

    s16x8 Bh[2][8], Bl[2][8];
#pragma unroll
    for (int t2 = 0; t2 < 2; ++t2) {
        int row = 16 * (2 * w + t2) + lr;
#pragma unroll
        for (int q = 0; q < 8; ++q) {
            int off = row * NS + 32 * q + 8 * lg;
            Bh[t2][q] = *(const s16x8*)(mh + off);
            Bl[t2][q] = *(const s16x8*)(ml + off);
        }
    }
    s16x8 KAh[2][4];
#pragma unroll
    for (int t2 = 0; t2 < 2; ++t2) {
        int row = 16 * (2 * w + t2) + lr;
#pragma unroll
        for (int q = 0; q < 4; ++q) {
            KAh[t2][q] = *(const s16x8*)(kah + row * MO + 32 * q + 8 * lg);
        }
    }

    const int b0 = (blk & 3) * 16;
    const int cc = blk >> 2;

#pragma unroll
    for (int jj = 0; jj < 8; ++jj) {
        int idx = jj * 512 + tid;
        int m = idx >> 8, col = idx & 255;
        ushort hu = 0;
        if constexpr (MODE == 4) {
            hu = cin[((long)(b0 + m) * 64 + cc) * NS + col];
        }
        int si = (m * NS + col) ^ ((m & 7) << 3);
        xh_s[0][si] = hu;
        xl_s[0][si] = 0;
    }

    const int st0 = 32 * w + 4 * lg;
    const int st1 = st0 + 16;

    const long ybase = ((long)(b0 + lr) * TT + cc * 16) * MO + 8 * lg;

    float4 yraw[8];
    auto load_y = [&](int s) {
#pragma unroll
        for (int q = 0; q < 4; ++q) {
            long off = ybase + (long)s * MO + 32 * q;
            yraw[2 * q] = *(const float4*)(y_g + off);
            yraw[2 * q + 1] = *(const float4*)(y_g + off + 4);
        }
    };
    auto compute_u = [&](f32x4& ua0, f32x4& ua1) {
        ua0 = f32x4{0.f, 0.f, 0.f, 0.f};
        ua1 = f32x4{0.f, 0.f, 0.f, 0.f};
#pragma unroll
        for (int q = 0; q < 4; ++q) {
            s16x8 yh, yl;
            conv8(yraw[2 * q], yraw[2 * q + 1], yh, yl);
            ua0 = mfma16(KAh[0][q], yh, ua0);
            ua0 = mfma16(KAh[0][q], yl, ua0);
            ua1 = mfma16(KAh[1][q], yh, ua1);
            ua1 = mfma16(KAh[1][q], yl, ua1);
        }
    };

    f32x4 up0, up1;
    load_y(0);
    compute_u(up0, up1);
    __syncthreads();

    for (int s = 0; s < S; ++s) {
        const int cur = s & 1, nxt = cur ^ 1;

        if (s + 1 < S) load_y(s + 1);

        f32x4 a0a = up0, a0b = {0.f, 0.f, 0.f, 0.f}, a0c = {0.f, 0.f, 0.f, 0.f};
        f32x4 a1a = up1, a1b = {0.f, 0.f, 0.f, 0.f}, a1c = {0.f, 0.f, 0.f, 0.f};
#pragma unroll
        for (int q = 0; q < 8; ++q) {
            int ridx = (lr * NS + 32 * q + 8 * lg) ^ ((lr & 7) << 3);
            s16x8 xh = *(const s16x8*)&xh_s[cur][ridx];
            s16x8 xl = *(const s16x8*)&xl_s[cur][ridx];
            a0a = mfma16(Bh[0][q], xh, a0a);
            a0b = mfma16(Bh[0][q], xl, a0b);
            a0c = mfma16(Bl[0][q], xh, a0c);
            a1a = mfma16(Bh[1][q], xh, a1a);
            a1b = mfma16(Bh[1][q], xl, a1b);
            a1c = mfma16(Bl[1][q], xh, a1c);
        }
        f32x4 acc0 = (a0a + a0b) + a0c;
        f32x4 acc1 = (a1a + a1b) + a1c;

        if (s + 1 < S) compute_u(up0, up1);

        uint h01a = pkbf2(acc0[0], acc0[1]), h23a = pkbf2(acc0[2], acc0[3]);
        uint h01b = pkbf2(acc1[0], acc1[1]), h23b = pkbf2(acc1[2], acc1[3]);

        if constexpr (MODE == 4) {
            long ob = ((long)(b0 + lr) * TT + cc * 16 + s) * NS;
            *(f32x4*)(outf + ob + st0) = acc0;
            *(f32x4*)(outf + ob + st1) = acc1;
        } else {
            if (s == S - 1) {
                long eb = ((long)(b0 + lr) * 64 + cc) * NS;
                *(uint2*)(ebf + eb + st0) = make_uint2(h01a, h23a);
                *(uint2*)(ebf + eb + st1) = make_uint2(h01b, h23b);
            }
        }

        if (s + 1 < S) {
            float la0 = acc0[0] - __uint_as_float(h01a << 16);
            float la1 = acc0[1] - __uint_as_float(h01a & 0xffff0000u);
            float la2 = acc0[2] - __uint_as_float(h23a << 16);
            float la3 = acc0[3] - __uint_as_float(h23a & 0xffff0000u);
            float lb0 = acc1[0] - __uint_as_float(h01b << 16);
            float lb1 = acc1[1] - __uint_as_float(h01b & 0xffff0000u);
            float lb2 = acc1[2] - __uint_as_float(h23b << 16);
            float lb3 = acc1[3] - __uint_as_float(h23b & 0xffff0000u);
            int wi0 = lr * NS + (st0 ^ ((lr & 7) << 3));
            int wi1 = lr * NS + (st1 ^ ((lr & 7) << 3));
            *(uint2*)&xh_s[nxt][wi0] = make_uint2(h01a, h23a);
            *(uint2*)&xh_s[nxt][wi1] = make_uint2(h01b, h23b);
            *(uint2*)&xl_s[nxt][wi0] = make_uint2(pkbf2(la0, la1), pkbf2(la2, la3));
            *(uint2*)&xl_s[nxt][wi1] = make_uint2(pkbf2(lb0, lb1), pkbf2(lb2, lb3));
        }
        __syncthreads();
    }
}

// ---------------- launcher ----------------

extern "C" void kernel_launch(void* const* d_in, const int* in_sizes, int n_in,
                              void* d_out, int out_size, void* d_ws, size_t ws_size,
                              hipStream_t stream) {
    const float* y = (const float*)d_in[0];
    const float* A = (const float*)d_in[1];
    const float* H = (const float*)d_in[2];
    const float* K = (const float*)d_in[3];
    float* out = (float*)d_out;

    float* ws = (float*)d_ws;
    const long MAT = (long)NS * NS;  // 65536
    float* Ta = ws + 0 * MAT;
    float* Tb = ws + 1 * MAT;
    ushort* usb = (ushort*)(ws + 2 * MAT);
    ushort* aeh = usb;
    ushort* ael = aeh + MAT;
    ushort* mh = ael + MAT;                 // A^16 hi
    ushort* ml = mh + MAT;
    ushort* m2h = ml + MAT;                 // A^128 hi
    ushort* m2l = m2h + MAT;
    ushort* kah = m2l + MAT;                // K hi: 32768
    ushort* e_buf = kah + (long)NS * MO;    // [64][64][256]
    ushort* cbuf = e_buf + (long)BB * 64 * NS;
    ushort* e2 = cbuf + (long)BB * 64 * NS; // [64][8][256]
    ushort* c2 = e2 + (long)BB * 8 * NS;
    int* bars = (int*)(ws + 26 * MAT);      // 16 ints, past all ushort buffers

    hipMemsetAsync(bars, 0, 16 * sizeof(int), stream);
    setup_kernel<<<256, 256, 0, stream>>>(K, H, A, Ta, Tb, kah, aeh, ael,
                                          mh, ml, m2h, m2l, bars);
    scan16_kernel<0><<<256, 512, 0, stream>>>(aeh, ael, kah, y, nullptr, nullptr, e_buf);
    mid_kernel<<<32, 512, 0, stream>>>(mh, ml, m2h, m2l, e_buf, e2, c2, cbuf, bars);
    scan16_kernel<4><<<256, 512, 0, stream>>>(aeh, ael, kah, y, cbuf, out, nullptr);
}